// Round 11
// baseline (2586.933 us; speedup 1.0000x reference)
//
#include <hip/hip_runtime.h>
#include <hip/hip_bf16.h>
#include <stdint.h>

// EncoderFLAX: x = emb[inputs]; xW = x@Wi + b; LSTM scan over S with Wh.
// B=256 S=256 V=32000 E=1024 H=1024. Outputs: [B,S,H] fp32, h [B,H], c [B,H].
//
// Round 11 = round 10 with the LDS staging ELIMINATED in the scan:
//   - A-fragments read directly from h in the XCD's L2 via
//     global_load_dwordx4 sc0 (L1 bypass; same producer-sc0/consumer-sc0
//     L2 path proven in r9 — only the consumer moved from LDS-staged to
//     direct). Kills: 64KB stage write + 320KB LDS reads + stage barrier
//     + vmcnt(0) stall per step (r10 postmortem's dominant ~2.2-2.4us).
//   - wave = (col-half cs, K-quarter kq): 16 cols x 4 gates x 256K, so
//     A duplication drops 4x -> 2x (128KB L2/block/step).
//   - 4-way reduction: kq=1..3 write partials to zsp[3] layers, barrier,
//     kq=0 adds + writes final zs; cell phase unchanged.
// Frozen: XCD groups via HW_REG_XCC_ID + slot counter, agent-atomic flags,
// sc0 h stores, permuted XW2, W register-resident, c in registers.
//
// ws layout (bytes):
//   WiT 0..8388608, WhT ..16777216, hb0 ..17301504, hb1 ..17825792,
//   X ..152043520 (first 4KB reused: [0..511] group flags, [512..519]
//   xcd slot counters — zeroed by zero_flags each launch), XW ..688914432

#define B_ 256
#define S_ 256
#define E_ 1024
#define H_ 1024
#define G_ 4096
#define M_ 65536

typedef float  f32x4  __attribute__((ext_vector_type(4)));
typedef __bf16 bf16x8 __attribute__((ext_vector_type(8)));

#define MFMA16(a, b, c) __builtin_amdgcn_mfma_f32_16x16x32_bf16((a), (b), (c), 0, 0, 0)

// sc0 16B load with literal offset (early-clobber dest: r5 lesson)
#define ALOAD(dst, ptr, OFF)                                            \
  asm volatile("global_load_dwordx4 %0, %1, off offset:" #OFF " sc0"    \
               : "=&v"(dst) : "v"(ptr) : "memory")

__device__ __forceinline__ void gload_lds16(const void* g, void* l) {
  __builtin_amdgcn_global_load_lds(
      (__attribute__((address_space(1))) void*)(g),
      (__attribute__((address_space(3))) void*)(l), 16, 0, 0);
}

__device__ __forceinline__ float sigm(float x) { return 1.f / (1.f + __expf(-x)); }
__device__ __forceinline__ float tanhfast(float x) {
  float e = __expf(-2.f * x);
  return (1.f - e) / (1.f + e);
}
__device__ __forceinline__ float bf_lo(unsigned v) { return __uint_as_float(v << 16); }
__device__ __forceinline__ float bf_hi(unsigned v) { return __uint_as_float(v & 0xffff0000u); }

// ---------------------------------------------------------------- zero init
__global__ __launch_bounds__(256) void zero_init(uint4* h16) {
  int i = blockIdx.x * 256 + threadIdx.x;
  uint4 z; z.x = z.y = z.z = z.w = 0u;
  if (i < 32768) h16[i] = z;            // hb0: 262144 bf16 = 32768 x 16B
}
__global__ __launch_bounds__(256) void zero_flags(unsigned* flags) {
  flags[blockIdx.x * 256 + threadIdx.x] = 0u;   // 1024 dwords (flags+counters)
}

// ------------------------------------------------- transpose+cast [1024][4096]
__global__ __launch_bounds__(256) void transpose_cast(const float* __restrict__ in,
                                                      __bf16* __restrict__ out) {
  __shared__ __bf16 tile[32][33];
  const int c0 = blockIdx.x * 32;
  const int r0 = blockIdx.y * 32;
  const int tx = threadIdx.x & 31, ty = threadIdx.x >> 5;
#pragma unroll
  for (int p = 0; p < 4; ++p) {
    const int rr = ty + p * 8;
    tile[rr][tx] = (__bf16)in[(size_t)(r0 + rr) * G_ + c0 + tx];
  }
  __syncthreads();
#pragma unroll
  for (int p = 0; p < 4; ++p) {
    const int rr = ty + p * 8;
    out[(size_t)(c0 + rr) * E_ + r0 + tx] = tile[tx][rr];
  }
}

// ------------------------------------------------------- embedding gather+cast
union U16b { uint4 v; __bf16 h[8]; };
__global__ __launch_bounds__(256) void gather_cast(const int* __restrict__ idx,
                                                   const float* __restrict__ emb,
                                                   __bf16* __restrict__ X) {
  const size_t gid  = (size_t)blockIdx.x * 256 + threadIdx.x;
  const size_t base = gid * 8;
  const int r = (int)(base >> 10);
  const int e = (int)(base & 1023);
  const int row = idx[r];
  const float4* s = (const float4*)(emb + (size_t)row * E_ + e);
  const float4 v0 = s[0], v1 = s[1];
  U16b u;
  u.h[0] = (__bf16)v0.x; u.h[1] = (__bf16)v0.y; u.h[2] = (__bf16)v0.z; u.h[3] = (__bf16)v0.w;
  u.h[4] = (__bf16)v1.x; u.h[5] = (__bf16)v1.y; u.h[6] = (__bf16)v1.z; u.h[7] = (__bf16)v1.w;
  *(uint4*)(X + base) = u.v;
}

// --------------------------------------------------- xW GEMM (m97 structure)
// Writes XW PERMUTED: elem offset = ((row*32 + cg)*4 + gate)*32 + col_in_cg.
__global__ __launch_bounds__(256) void gemm_xw(const __bf16* __restrict__ X,
                                               const __bf16* __restrict__ WiT,
                                               const float* __restrict__ bias,
                                               __bf16* __restrict__ XW2) {
  __shared__ __bf16 As[128 * 32];
  __shared__ __bf16 Bs[128 * 32];
  __shared__ __bf16 eps[64][136];
  const int tid = threadIdx.x;
  const int lane = tid & 63;
  const int wid = tid >> 6;
  const int bn = blockIdx.x & 31;
  const int bm = blockIdx.x >> 5;
  const int row0 = bm * 128, col0 = bn * 128;
  const int wr = (wid >> 1) * 64, wc = (wid & 1) * 64;
  const int srow = tid >> 2, schunk = tid & 3;
  const char* gA = (const char*)(X + (size_t)(row0 + srow) * E_) + schunk * 16;
  const char* gB = (const char*)(WiT + (size_t)(col0 + srow) * E_) + schunk * 16;
  char* lA = (char*)As + wid * 1024;
  char* lB = (char*)Bs + wid * 1024;
  const int fr = lane & 15, kb = lane >> 4;

  f32x4 acc[4][4] = {};

  for (int kt = 0; kt < 32; ++kt) {
    gload_lds16(gA + kt * 64,              lA);
    gload_lds16(gA + kt * 64 + 64 * 2048,  lA + 4096);
    gload_lds16(gB + kt * 64,              lB);
    gload_lds16(gB + kt * 64 + 64 * 2048,  lB + 4096);
    __syncthreads();
    bf16x8 a[4], b[4];
#pragma unroll
    for (int m = 0; m < 4; ++m)
      a[m] = *(const bf16x8*)((const char*)As + (wr + m * 16 + fr) * 64 + kb * 16);
#pragma unroll
    for (int n = 0; n < 4; ++n)
      b[n] = *(const bf16x8*)((const char*)Bs + (wc + n * 16 + fr) * 64 + kb * 16);
#pragma unroll
    for (int m = 0; m < 4; ++m)
#pragma unroll
      for (int n = 0; n < 4; ++n)
        acc[m][n] = MFMA16(a[m], b[n], acc[m][n]);
    __syncthreads();
  }

  float bv[4];
#pragma unroll
  for (int n = 0; n < 4; ++n) bv[n] = bias[col0 + wc + n * 16 + fr];

  const int gate = col0 >> 10;             // 128-col tile spans one gate
  const int cg0  = (col0 & 1023) >> 5;     // first of 4 col-groups

#pragma unroll
  for (int h = 0; h < 2; ++h) {
    if ((wid >> 1) == h) {
#pragma unroll
      for (int m = 0; m < 4; ++m)
#pragma unroll
        for (int n = 0; n < 4; ++n)
#pragma unroll
          for (int r = 0; r < 4; ++r)
            eps[m * 16 + kb * 4 + r][wc + n * 16 + fr] = (__bf16)(acc[m][n][r] + bv[n]);
    }
    __syncthreads();
    {
      const int row = tid >> 2, ch = tid & 3;
      const int r_m = row0 + h * 64 + row;
      const uint4* s = (const uint4*)&eps[row][ch * 32];
      uint4* d = (uint4*)(XW2 + ((size_t)r_m * 32 + (cg0 + ch)) * 128 + gate * 32);
#pragma unroll
      for (int i = 0; i < 4; ++i) d[i] = s[i];
    }
    __syncthreads();
  }
}

// ----------------------------------------------------- persistent LSTM scan
// 256 blocks (1/CU, guaranteed by VGPR>128), 512 threads.
// Block = 32 batch rows x 32 h-cols. Wave = (col-half cs, K-quarter kq):
// 16 cols x 4 gates x 256 K; W[4][8] register-resident; A-frags direct
// from L2 (sc0), no LDS staging. 4-way K reduction through zsp.
__global__ __launch_bounds__(512, 2) void lstm_scan(
    const __bf16* __restrict__ WhT, const __bf16* __restrict__ XW2,
    __bf16* __restrict__ hb0, __bf16* __restrict__ hb1,
    float* __restrict__ outp, float* __restrict__ hfin,
    float* __restrict__ cfin, unsigned* __restrict__ flags) {
  __shared__ float zsp[3][4][32][34];  // kq=1..3 partials (51KB)
  __shared__ float zs[4][32][34];      // final gate values (17KB)
  __shared__ int   sgrp[2];
  const int tid = threadIdx.x;
  const int lane = tid & 63;
  const int wid = tid >> 6;

  // ---- runtime XCD grouping: bg = XCC_ID, cg = slot within the XCD ----
  if (tid == 0) {
    unsigned xcd;
    asm volatile("s_getreg_b32 %0, hwreg(HW_REG_XCC_ID)" : "=s"(xcd));
    xcd &= 7u;
    unsigned slot = __hip_atomic_fetch_add(&flags[512 + xcd], 1u,
                                           __ATOMIC_RELAXED, __HIP_MEMORY_SCOPE_AGENT);
    sgrp[0] = (int)xcd;
    sgrp[1] = (int)(slot & 31u);
  }
  __syncthreads();
  const int bg = sgrp[0];
  const int cg = sgrp[1];
  const int b0 = bg * 32;
  const int c0 = cg * 32;
  unsigned* grpflags = flags + bg * 64;        // 32 flags, 2 cachelines/group

  const int cs = wid & 1;      // col half (16 cols)
  const int kq = wid >> 1;     // K quarter: [kq*256, kq*256+256)
  const int fr = lane & 15, kb = lane >> 4;

  // ---- Wh slice -> registers, once: 4 gates x 16 cols x 256 K ----
  bf16x8 W[4][8];
#pragma unroll
  for (int g = 0; g < 4; ++g) {
    const __bf16* wbase = WhT + (size_t)(g * 1024 + c0 + cs * 16 + fr) * H_ +
                          kq * 256 + kb * 8;
#pragma unroll
    for (int ks = 0; ks < 8; ++ks)
      W[g][ks] = *(const bf16x8*)(wbase + ks * 32);
  }

  const int crow = tid >> 4, ccolb = (tid & 15) * 2;
  const size_t sidx = (size_t)(b0 + crow) * H_ + c0 + ccolb;
  const __bf16* xwrow = XW2 + ((size_t)(b0 + crow) * S_ * 32 + cg) * 128 + ccolb;
  float creg0 = 0.f, creg1 = 0.f;

#pragma unroll 1
  for (int t = 0; t < S_; ++t) {
    const __bf16* hin = (t & 1) ? hb1 : hb0;
    __bf16* hout = (t & 1) ? hb0 : hb1;

    // XW cell inputs for step t (plain cached loads, issued early).
    const __bf16* p = xwrow + (size_t)t * 4096;
    const unsigned xw0 = *(const unsigned*)(p);
    const unsigned xw1 = *(const unsigned*)(p + 32);
    const unsigned xw2 = *(const unsigned*)(p + 64);
    const unsigned xw3 = *(const unsigned*)(p + 96);

    // ---- wait for h(t-1) of OUR bg group (32 same-XCD producers) ----
    if (t > 0) {
      if (tid < 32) {
        const unsigned tgt = (unsigned)t;
        while (__hip_atomic_load(&grpflags[tid], __ATOMIC_RELAXED,
                                 __HIP_MEMORY_SCOPE_AGENT) < tgt)
          __builtin_amdgcn_s_sleep(1);
      }
      __syncthreads();
    }

    // ---- MFMA: A-frags direct from L2 (sc0), per row-tile batches ----
    f32x4 acc[2][4] = {};   // [row-tile][gate]
    {
      const __bf16* a0p = hin + (size_t)(b0 + fr) * H_ + kq * 256 + kb * 8;
#pragma unroll
      for (int rt = 0; rt < 2; ++rt) {
        const __bf16* ap = a0p + (size_t)rt * 16 * H_;
        uint4 sv[8];
        ALOAD(sv[0], ap, 0);
        ALOAD(sv[1], ap, 64);
        ALOAD(sv[2], ap, 128);
        ALOAD(sv[3], ap, 192);
        ALOAD(sv[4], ap, 256);
        ALOAD(sv[5], ap, 320);
        ALOAD(sv[6], ap, 384);
        ALOAD(sv[7], ap, 448);
        asm volatile("s_waitcnt vmcnt(0)" ::: "memory");
        __builtin_amdgcn_sched_barrier(0);
#pragma unroll
        for (int ks = 0; ks < 8; ++ks) {
          const bf16x8 av = *(const bf16x8*)&sv[ks];
#pragma unroll
          for (int g = 0; g < 4; ++g)
            acc[rt][g] = MFMA16(av, W[g][ks], acc[rt][g]);
        }
      }
    }

    // ---- 4-way K reduction: kq=1..3 write partials, kq=0 adds+finalizes ----
    if (kq > 0) {
#pragma unroll
      for (int rt = 0; rt < 2; ++rt)
#pragma unroll
        for (int g = 0; g < 4; ++g)
#pragma unroll
          for (int r = 0; r < 4; ++r)
            zsp[kq - 1][g][rt * 16 + kb * 4 + r][cs * 16 + fr] = acc[rt][g][r];
    }
    __syncthreads();
    if (kq == 0) {
#pragma unroll
      for (int rt = 0; rt < 2; ++rt)
#pragma unroll
        for (int g = 0; g < 4; ++g)
#pragma unroll
          for (int r = 0; r < 4; ++r) {
            const int row = rt * 16 + kb * 4 + r;
            const int col = cs * 16 + fr;
            zs[g][row][col] = acc[rt][g][r] + zsp[0][g][row][col] +
                              zsp[1][g][row][col] + zsp[2][g][row][col];
          }
    }
    __syncthreads();

    // ---- cell (fp32), c in registers ----
    const float2 zi2 = *(const float2*)&zs[0][crow][ccolb];
    const float2 zf2 = *(const float2*)&zs[1][crow][ccolb];
    const float2 zg2 = *(const float2*)&zs[2][crow][ccolb];
    const float2 zo2 = *(const float2*)&zs[3][crow][ccolb];
    const float zi0 = zi2.x + bf_lo(xw0), zi1 = zi2.y + bf_hi(xw0);
    const float zf0 = zf2.x + bf_lo(xw1), zf1 = zf2.y + bf_hi(xw1);
    const float zg0 = zg2.x + bf_lo(xw2), zg1 = zg2.y + bf_hi(xw2);
    const float zo0 = zo2.x + bf_lo(xw3), zo1 = zo2.y + bf_hi(xw3);
    const float cv0 = sigm(zf0) * creg0 + sigm(zi0) * tanhfast(zg0);
    const float cv1 = sigm(zf1) * creg1 + sigm(zi1) * tanhfast(zg1);
    creg0 = cv0; creg1 = cv1;
    const float hv0 = sigm(zo0) * tanhfast(cv0);
    const float hv1 = sigm(zo1) * tanhfast(cv1);

    union { __bf16 h[2]; unsigned u; } up;
    up.h[0] = (__bf16)hv0; up.h[1] = (__bf16)hv1;
    float2 o2; o2.x = hv0; o2.y = hv1;

    // h store: sc0-only -> lands in our XCD's L2 (consumers are same-XCD)
    {
      void* dst = (void*)(hout + sidx);
      asm volatile("global_store_dword %0, %1, off sc0"
                   :: "v"(dst), "v"(up.u) : "memory");
    }

    if (t == S_ - 1) {
      *(float2*)(outp + ((size_t)(b0 + crow) * S_ + t) * H_ + c0 + ccolb) = o2;
      float2 c2; c2.x = cv0; c2.y = cv1;
      *(float2*)(hfin + sidx) = o2;
      *(float2*)(cfin + sidx) = c2;
    } else {
      asm volatile("s_waitcnt vmcnt(0)" ::: "memory");   // h committed to L2
      __builtin_amdgcn_s_barrier();
      if (tid == 0)
        __hip_atomic_store(&grpflags[cg], (unsigned)(t + 1),
                           __ATOMIC_RELAXED, __HIP_MEMORY_SCOPE_AGENT);
      // outp store AFTER the flag: a full step of slack to drain
      *(float2*)(outp + ((size_t)(b0 + crow) * S_ + t) * H_ + c0 + ccolb) = o2;
    }
  }
}

// ----------------------------------------------------------------- launcher
extern "C" void kernel_launch(void* const* d_in, const int* in_sizes, int n_in,
                              void* d_out, int out_size, void* d_ws, size_t ws_size,
                              hipStream_t stream) {
  const int*   inp  = (const int*)d_in[0];
  const float* emb  = (const float*)d_in[1];
  const float* Wi   = (const float*)d_in[2];
  const float* Wh   = (const float*)d_in[3];
  const float* bias = (const float*)d_in[4];

  char* ws = (char*)d_ws;
  __bf16* WiT = (__bf16*)(ws);
  __bf16* WhT = (__bf16*)(ws + 8388608);
  __bf16* hb0 = (__bf16*)(ws + 16777216);
  __bf16* hb1 = (__bf16*)(ws + 17301504);
  __bf16* X   = (__bf16*)(ws + 17825792);
  __bf16* XW2 = (__bf16*)(ws + 152043520);
  unsigned* flags = (unsigned*)(ws + 17825792);  // overlays dead X during scan

  float* outp = (float*)d_out;
  float* hfin = outp + (size_t)M_ * H_;
  float* cfin = hfin + (size_t)B_ * H_;

  zero_init<<<128, 256, 0, stream>>>((uint4*)hb0);
  transpose_cast<<<dim3(128, 32), 256, 0, stream>>>(Wi, WiT);
  transpose_cast<<<dim3(128, 32), 256, 0, stream>>>(Wh, WhT);
  gather_cast<<<32768, 256, 0, stream>>>(inp, emb, X);
  gemm_xw<<<16384, 256, 0, stream>>>(X, WiT, bias, XW2);
  zero_flags<<<4, 256, 0, stream>>>(flags);   // X is dead from here on
  lstm_scan<<<256, 512, 0, stream>>>(WhT, XW2, hb0, hb1, outp, hfin, cfin, flags);
}

// Round 12
// 2130.802 us; speedup vs baseline: 1.2141x; 1.2141x over previous
//
#include <hip/hip_runtime.h>
#include <hip/hip_bf16.h>
#include <stdint.h>

// EncoderFLAX: x = emb[inputs]; xW = x@Wi + b; LSTM scan over S with Wh.
// B=256 S=256 V=32000 E=1024 H=1024. Outputs: [B,S,H] fp32, h [B,H], c [B,H].
//
// Round 12 = r10 staging + r11 wave split (hybrid of two PROVEN pieces):
//   - A staged to LDS once per step (r10's coalesced path; r11's direct-L2
//     variant regressed: scattered 16-row loads + mid-phase vmcnt(0) with
//     all waves in lockstep exposed L2 latency twice per step).
//   - wave = (col-half cs, K-quarter kq): 16 cols x 4 gates x 256 K, W[4][8]
//     register-resident (r11-verified layout) -> per-wave As read 16KB,
//     block total 128KB/step (r10: 256KB — its dominant term).
//   - 4-way reduction via zsp[3]+zs (r11-verified indexing).
// Frozen: XCD groups (HW_REG_XCC_ID+slot), agent-atomic flags, sc0 h
// exchange, permuted XW2, c in registers, outp store after flag.
//
// ws layout (bytes):
//   WiT 0..8388608, WhT ..16777216, hb0 ..17301504, hb1 ..17825792,
//   X ..152043520 (first 4KB reused: [0..511] group flags, [512..519]
//   xcd slot counters — zeroed by zero_flags each launch), XW ..688914432

#define B_ 256
#define S_ 256
#define E_ 1024
#define H_ 1024
#define G_ 4096
#define M_ 65536

typedef float  f32x4  __attribute__((ext_vector_type(4)));
typedef __bf16 bf16x8 __attribute__((ext_vector_type(8)));

#define MFMA16(a, b, c) __builtin_amdgcn_mfma_f32_16x16x32_bf16((a), (b), (c), 0, 0, 0)

__device__ __forceinline__ void gload_lds16(const void* g, void* l) {
  __builtin_amdgcn_global_load_lds(
      (__attribute__((address_space(1))) void*)(g),
      (__attribute__((address_space(3))) void*)(l), 16, 0, 0);
}

__device__ __forceinline__ float sigm(float x) { return 1.f / (1.f + __expf(-x)); }
__device__ __forceinline__ float tanhfast(float x) {
  float e = __expf(-2.f * x);
  return (1.f - e) / (1.f + e);
}
__device__ __forceinline__ float bf_lo(unsigned v) { return __uint_as_float(v << 16); }
__device__ __forceinline__ float bf_hi(unsigned v) { return __uint_as_float(v & 0xffff0000u); }

// ---------------------------------------------------------------- zero init
__global__ __launch_bounds__(256) void zero_init(uint4* h16) {
  int i = blockIdx.x * 256 + threadIdx.x;
  uint4 z; z.x = z.y = z.z = z.w = 0u;
  if (i < 32768) h16[i] = z;            // hb0: 262144 bf16 = 32768 x 16B
}
__global__ __launch_bounds__(256) void zero_flags(unsigned* flags) {
  flags[blockIdx.x * 256 + threadIdx.x] = 0u;   // 1024 dwords (flags+counters)
}

// ------------------------------------------------- transpose+cast [1024][4096]
__global__ __launch_bounds__(256) void transpose_cast(const float* __restrict__ in,
                                                      __bf16* __restrict__ out) {
  __shared__ __bf16 tile[32][33];
  const int c0 = blockIdx.x * 32;
  const int r0 = blockIdx.y * 32;
  const int tx = threadIdx.x & 31, ty = threadIdx.x >> 5;
#pragma unroll
  for (int p = 0; p < 4; ++p) {
    const int rr = ty + p * 8;
    tile[rr][tx] = (__bf16)in[(size_t)(r0 + rr) * G_ + c0 + tx];
  }
  __syncthreads();
#pragma unroll
  for (int p = 0; p < 4; ++p) {
    const int rr = ty + p * 8;
    out[(size_t)(c0 + rr) * E_ + r0 + tx] = tile[tx][rr];
  }
}

// ------------------------------------------------------- embedding gather+cast
union U16b { uint4 v; __bf16 h[8]; };
__global__ __launch_bounds__(256) void gather_cast(const int* __restrict__ idx,
                                                   const float* __restrict__ emb,
                                                   __bf16* __restrict__ X) {
  const size_t gid  = (size_t)blockIdx.x * 256 + threadIdx.x;
  const size_t base = gid * 8;
  const int r = (int)(base >> 10);
  const int e = (int)(base & 1023);
  const int row = idx[r];
  const float4* s = (const float4*)(emb + (size_t)row * E_ + e);
  const float4 v0 = s[0], v1 = s[1];
  U16b u;
  u.h[0] = (__bf16)v0.x; u.h[1] = (__bf16)v0.y; u.h[2] = (__bf16)v0.z; u.h[3] = (__bf16)v0.w;
  u.h[4] = (__bf16)v1.x; u.h[5] = (__bf16)v1.y; u.h[6] = (__bf16)v1.z; u.h[7] = (__bf16)v1.w;
  *(uint4*)(X + base) = u.v;
}

// --------------------------------------------------- xW GEMM (m97 structure)
// Writes XW PERMUTED: elem offset = ((row*32 + cg)*4 + gate)*32 + col_in_cg.
__global__ __launch_bounds__(256) void gemm_xw(const __bf16* __restrict__ X,
                                               const __bf16* __restrict__ WiT,
                                               const float* __restrict__ bias,
                                               __bf16* __restrict__ XW2) {
  __shared__ __bf16 As[128 * 32];
  __shared__ __bf16 Bs[128 * 32];
  __shared__ __bf16 eps[64][136];
  const int tid = threadIdx.x;
  const int lane = tid & 63;
  const int wid = tid >> 6;
  const int bn = blockIdx.x & 31;
  const int bm = blockIdx.x >> 5;
  const int row0 = bm * 128, col0 = bn * 128;
  const int wr = (wid >> 1) * 64, wc = (wid & 1) * 64;
  const int srow = tid >> 2, schunk = tid & 3;
  const char* gA = (const char*)(X + (size_t)(row0 + srow) * E_) + schunk * 16;
  const char* gB = (const char*)(WiT + (size_t)(col0 + srow) * E_) + schunk * 16;
  char* lA = (char*)As + wid * 1024;
  char* lB = (char*)Bs + wid * 1024;
  const int fr = lane & 15, kb = lane >> 4;

  f32x4 acc[4][4] = {};

  for (int kt = 0; kt < 32; ++kt) {
    gload_lds16(gA + kt * 64,              lA);
    gload_lds16(gA + kt * 64 + 64 * 2048,  lA + 4096);
    gload_lds16(gB + kt * 64,              lB);
    gload_lds16(gB + kt * 64 + 64 * 2048,  lB + 4096);
    __syncthreads();
    bf16x8 a[4], b[4];
#pragma unroll
    for (int m = 0; m < 4; ++m)
      a[m] = *(const bf16x8*)((const char*)As + (wr + m * 16 + fr) * 64 + kb * 16);
#pragma unroll
    for (int n = 0; n < 4; ++n)
      b[n] = *(const bf16x8*)((const char*)Bs + (wc + n * 16 + fr) * 64 + kb * 16);
#pragma unroll
    for (int m = 0; m < 4; ++m)
#pragma unroll
      for (int n = 0; n < 4; ++n)
        acc[m][n] = MFMA16(a[m], b[n], acc[m][n]);
    __syncthreads();
  }

  float bv[4];
#pragma unroll
  for (int n = 0; n < 4; ++n) bv[n] = bias[col0 + wc + n * 16 + fr];

  const int gate = col0 >> 10;             // 128-col tile spans one gate
  const int cg0  = (col0 & 1023) >> 5;     // first of 4 col-groups

#pragma unroll
  for (int h = 0; h < 2; ++h) {
    if ((wid >> 1) == h) {
#pragma unroll
      for (int m = 0; m < 4; ++m)
#pragma unroll
        for (int n = 0; n < 4; ++n)
#pragma unroll
          for (int r = 0; r < 4; ++r)
            eps[m * 16 + kb * 4 + r][wc + n * 16 + fr] = (__bf16)(acc[m][n][r] + bv[n]);
    }
    __syncthreads();
    {
      const int row = tid >> 2, ch = tid & 3;
      const int r_m = row0 + h * 64 + row;
      const uint4* s = (const uint4*)&eps[row][ch * 32];
      uint4* d = (uint4*)(XW2 + ((size_t)r_m * 32 + (cg0 + ch)) * 128 + gate * 32);
#pragma unroll
      for (int i = 0; i < 4; ++i) d[i] = s[i];
    }
    __syncthreads();
  }
}

// ----------------------------------------------------- persistent LSTM scan
// 256 blocks (1/CU), 512 threads. Block = 32 batch rows x 32 h-cols.
// Wave = (col-half cs, K-quarter kq): 16 cols x 4 gates x 256 K from LDS;
// W[4][8] register-resident; 4-way K reduction via zsp; XCD-local groups.
__global__ __launch_bounds__(512, 2) void lstm_scan(
    const __bf16* __restrict__ WhT, const __bf16* __restrict__ XW2,
    __bf16* __restrict__ hb0, __bf16* __restrict__ hb1,
    float* __restrict__ outp, float* __restrict__ hfin,
    float* __restrict__ cfin, unsigned* __restrict__ flags) {
  __shared__ __bf16 As[32 * 1024];     // 64 KB, XOR-swizzled 16B chunks
  __shared__ float zsp[3][4][32][34];  // kq=1..3 partials (51KB)
  __shared__ float zs[4][32][34];      // final gate values (17KB)
  __shared__ int   sgrp[2];
  const int tid = threadIdx.x;
  const int lane = tid & 63;
  const int wid = tid >> 6;

  // ---- runtime XCD grouping: bg = XCC_ID, cg = slot within the XCD ----
  if (tid == 0) {
    unsigned xcd;
    asm volatile("s_getreg_b32 %0, hwreg(HW_REG_XCC_ID)" : "=s"(xcd));
    xcd &= 7u;
    unsigned slot = __hip_atomic_fetch_add(&flags[512 + xcd], 1u,
                                           __ATOMIC_RELAXED, __HIP_MEMORY_SCOPE_AGENT);
    sgrp[0] = (int)xcd;
    sgrp[1] = (int)(slot & 31u);
  }
  __syncthreads();
  const int bg = sgrp[0];
  const int cg = sgrp[1];
  const int b0 = bg * 32;
  const int c0 = cg * 32;
  unsigned* grpflags = flags + bg * 64;        // 32 flags, 2 cachelines/group

  const int cs = wid & 1;      // col half (16 cols)
  const int kq = wid >> 1;     // K quarter: [kq*256, kq*256+256)
  const int fr = lane & 15, kb = lane >> 4;

  // ---- Wh slice -> registers, once: 4 gates x 16 cols x 256 K ----
  bf16x8 W[4][8];
#pragma unroll
  for (int g = 0; g < 4; ++g) {
    const __bf16* wbase = WhT + (size_t)(g * 1024 + c0 + cs * 16 + fr) * H_ +
                          kq * 256 + kb * 8;
#pragma unroll
    for (int ks = 0; ks < 8; ++ks)
      W[g][ks] = *(const bf16x8*)(wbase + ks * 32);
  }

  const int crow = tid >> 4, ccolb = (tid & 15) * 2;
  const size_t sidx = (size_t)(b0 + crow) * H_ + c0 + ccolb;
  const __bf16* xwrow = XW2 + ((size_t)(b0 + crow) * S_ * 32 + cg) * 128 + ccolb;
  float creg0 = 0.f, creg1 = 0.f;

#pragma unroll 1
  for (int t = 0; t < S_; ++t) {
    const __bf16* hin = (t & 1) ? hb1 : hb0;
    __bf16* hout = (t & 1) ? hb0 : hb1;

    // XW cell inputs for step t (plain cached loads, issued early).
    const __bf16* p = xwrow + (size_t)t * 4096;
    const unsigned xw0 = *(const unsigned*)(p);
    const unsigned xw1 = *(const unsigned*)(p + 32);
    const unsigned xw2 = *(const unsigned*)(p + 64);
    const unsigned xw3 = *(const unsigned*)(p + 96);

    // ---- wait for h(t-1) of OUR bg group (32 same-XCD producers) ----
    if (t > 0) {
      if (tid < 32) {
        const unsigned tgt = (unsigned)t;
        while (__hip_atomic_load(&grpflags[tid], __ATOMIC_RELAXED,
                                 __HIP_MEMORY_SCOPE_AGENT) < tgt)
          __builtin_amdgcn_s_sleep(1);
      }
      __syncthreads();
    }

    // ---- stage h rows [b0,b0+32): sc0 loads -> swizzled ds_write ----
    {
      uint4 sv[8];
#pragma unroll
      for (int i = 0; i < 8; ++i) {
        const int ci = i * 512 + tid;
        const int row = ci >> 7, cch = ci & 127;
        const void* src = (const char*)(hin + (size_t)(b0 + row) * H_) + cch * 16;
        asm volatile("global_load_dwordx4 %0, %1, off sc0"
                     : "=&v"(sv[i]) : "v"(src) : "memory");
      }
      asm volatile("s_waitcnt vmcnt(0)" ::: "memory");
      __builtin_amdgcn_sched_barrier(0);
#pragma unroll
      for (int i = 0; i < 8; ++i) {
        const int ci = i * 512 + tid;
        const int row = ci >> 7, cch = ci & 127;
        *(uint4*)((char*)As + row * 2048 + ((cch ^ (row & 7)) * 16)) = sv[i];
      }
    }
    __syncthreads();

    // ---- MFMA: 32 rows x (16 cols x 4 gates) x 256 K per wave from LDS ----
    f32x4 acc[2][4] = {};   // [row-tile][gate]
#pragma unroll
    for (int ks = 0; ks < 8; ++ks) {
      const int ck = kq * 32 + ks * 4 + kb;
      bf16x8 alo = *(const bf16x8*)((const char*)As + fr * 2048 +
                                    ((ck ^ (fr & 7)) * 16));
      bf16x8 ahi = *(const bf16x8*)((const char*)As + (16 + fr) * 2048 +
                                    ((ck ^ (fr & 7)) * 16));
#pragma unroll
      for (int g = 0; g < 4; ++g) {
        acc[0][g] = MFMA16(alo, W[g][ks], acc[0][g]);
        acc[1][g] = MFMA16(ahi, W[g][ks], acc[1][g]);
      }
    }

    // ---- 4-way K reduction: kq=1..3 write partials, kq=0 adds+finalizes ----
    if (kq > 0) {
#pragma unroll
      for (int rt = 0; rt < 2; ++rt)
#pragma unroll
        for (int g = 0; g < 4; ++g)
#pragma unroll
          for (int r = 0; r < 4; ++r)
            zsp[kq - 1][g][rt * 16 + kb * 4 + r][cs * 16 + fr] = acc[rt][g][r];
    }
    __syncthreads();
    if (kq == 0) {
#pragma unroll
      for (int rt = 0; rt < 2; ++rt)
#pragma unroll
        for (int g = 0; g < 4; ++g)
#pragma unroll
          for (int r = 0; r < 4; ++r) {
            const int row = rt * 16 + kb * 4 + r;
            const int col = cs * 16 + fr;
            zs[g][row][col] = acc[rt][g][r] + zsp[0][g][row][col] +
                              zsp[1][g][row][col] + zsp[2][g][row][col];
          }
    }
    __syncthreads();

    // ---- cell (fp32), c in registers ----
    const float2 zi2 = *(const float2*)&zs[0][crow][ccolb];
    const float2 zf2 = *(const float2*)&zs[1][crow][ccolb];
    const float2 zg2 = *(const float2*)&zs[2][crow][ccolb];
    const float2 zo2 = *(const float2*)&zs[3][crow][ccolb];
    const float zi0 = zi2.x + bf_lo(xw0), zi1 = zi2.y + bf_hi(xw0);
    const float zf0 = zf2.x + bf_lo(xw1), zf1 = zf2.y + bf_hi(xw1);
    const float zg0 = zg2.x + bf_lo(xw2), zg1 = zg2.y + bf_hi(xw2);
    const float zo0 = zo2.x + bf_lo(xw3), zo1 = zo2.y + bf_hi(xw3);
    const float cv0 = sigm(zf0) * creg0 + sigm(zi0) * tanhfast(zg0);
    const float cv1 = sigm(zf1) * creg1 + sigm(zi1) * tanhfast(zg1);
    creg0 = cv0; creg1 = cv1;
    const float hv0 = sigm(zo0) * tanhfast(cv0);
    const float hv1 = sigm(zo1) * tanhfast(cv1);

    union { __bf16 h[2]; unsigned u; } up;
    up.h[0] = (__bf16)hv0; up.h[1] = (__bf16)hv1;
    float2 o2; o2.x = hv0; o2.y = hv1;

    // h store: sc0-only -> lands in our XCD's L2 (consumers are same-XCD)
    {
      void* dst = (void*)(hout + sidx);
      asm volatile("global_store_dword %0, %1, off sc0"
                   :: "v"(dst), "v"(up.u) : "memory");
    }

    if (t == S_ - 1) {
      *(float2*)(outp + ((size_t)(b0 + crow) * S_ + t) * H_ + c0 + ccolb) = o2;
      float2 c2; c2.x = cv0; c2.y = cv1;
      *(float2*)(hfin + sidx) = o2;
      *(float2*)(cfin + sidx) = c2;
    } else {
      asm volatile("s_waitcnt vmcnt(0)" ::: "memory");   // h committed to L2
      __builtin_amdgcn_s_barrier();
      if (tid == 0)
        __hip_atomic_store(&grpflags[cg], (unsigned)(t + 1),
                           __ATOMIC_RELAXED, __HIP_MEMORY_SCOPE_AGENT);
      // outp store AFTER the flag: a full step of slack to drain
      *(float2*)(outp + ((size_t)(b0 + crow) * S_ + t) * H_ + c0 + ccolb) = o2;
    }
  }
}

// ----------------------------------------------------------------- launcher
extern "C" void kernel_launch(void* const* d_in, const int* in_sizes, int n_in,
                              void* d_out, int out_size, void* d_ws, size_t ws_size,
                              hipStream_t stream) {
  const int*   inp  = (const int*)d_in[0];
  const float* emb  = (const float*)d_in[1];
  const float* Wi   = (const float*)d_in[2];
  const float* Wh   = (const float*)d_in[3];
  const float* bias = (const float*)d_in[4];

  char* ws = (char*)d_ws;
  __bf16* WiT = (__bf16*)(ws);
  __bf16* WhT = (__bf16*)(ws + 8388608);
  __bf16* hb0 = (__bf16*)(ws + 16777216);
  __bf16* hb1 = (__bf16*)(ws + 17301504);
  __bf16* X   = (__bf16*)(ws + 17825792);
  __bf16* XW2 = (__bf16*)(ws + 152043520);
  unsigned* flags = (unsigned*)(ws + 17825792);  // overlays dead X during scan

  float* outp = (float*)d_out;
  float* hfin = outp + (size_t)M_ * H_;
  float* cfin = hfin + (size_t)B_ * H_;

  zero_init<<<128, 256, 0, stream>>>((uint4*)hb0);
  transpose_cast<<<dim3(128, 32), 256, 0, stream>>>(Wi, WiT);
  transpose_cast<<<dim3(128, 32), 256, 0, stream>>>(Wh, WhT);
  gather_cast<<<32768, 256, 0, stream>>>(inp, emb, X);
  gemm_xw<<<16384, 256, 0, stream>>>(X, WiT, bias, XW2);
  zero_flags<<<4, 256, 0, stream>>>(flags);   // X is dead from here on
  lstm_scan<<<256, 512, 0, stream>>>(WhT, XW2, hb0, hb1, outp, hfin, cfin, flags);
}

// Round 14
// 1996.337 us; speedup vs baseline: 1.2958x; 1.0674x over previous
//
#include <hip/hip_runtime.h>
#include <hip/hip_bf16.h>
#include <stdint.h>

// EncoderFLAX: x = emb[inputs]; xW = x@Wi + b; LSTM scan over S with Wh.
// B=256 S=256 V=32000 E=1024 H=1024. Outputs: [B,S,H] fp32, h [B,H], c [B,H].
//
// Round 14 = round 10 (last fully-proven scan) + merged zs2 reduction ONLY.
//   r13's sc0-only flag signaling HUNG (poll can spin on a stale-clean L2
//   line that the producer's non-atomic store never updates). Hard rule now:
//   flags = agent-scope atomics (proven r6-r12); raw sc0 is for bulk payload
//   (h exchange) only.
//   merged reduce (kept from r13, block-local, math == r10's two-phase):
//   both kh waves write their own zs2 layer, ONE barrier, cell adds layers
//   -> removes serial kh0-add + one barrier vs r10.
// Frozen: (gate,K-half) waves + W[2][16] register-resident Wh (r8/r10),
// XCD groups via XCC_ID+slot counter (r9), sc0 h exchange (r9), permuted
// XW2 (r6), reg-staged swizzled As staging (r3), c in registers (r2).
//
// ws layout (bytes):
//   WiT 0..8388608, WhT ..16777216, hb0 ..17301504, hb1 ..17825792,
//   X ..152043520 (first 4KB reused: [0..511] group flags, [512..519]
//   xcd slot counters — zeroed by zero_flags each launch), XW ..688914432

#define B_ 256
#define S_ 256
#define E_ 1024
#define H_ 1024
#define G_ 4096
#define M_ 65536

typedef float  f32x4  __attribute__((ext_vector_type(4)));
typedef __bf16 bf16x8 __attribute__((ext_vector_type(8)));

#define MFMA16(a, b, c) __builtin_amdgcn_mfma_f32_16x16x32_bf16((a), (b), (c), 0, 0, 0)

__device__ __forceinline__ void gload_lds16(const void* g, void* l) {
  __builtin_amdgcn_global_load_lds(
      (__attribute__((address_space(1))) void*)(g),
      (__attribute__((address_space(3))) void*)(l), 16, 0, 0);
}

__device__ __forceinline__ float sigm(float x) { return 1.f / (1.f + __expf(-x)); }
__device__ __forceinline__ float tanhfast(float x) {
  float e = __expf(-2.f * x);
  return (1.f - e) / (1.f + e);
}
__device__ __forceinline__ float bf_lo(unsigned v) { return __uint_as_float(v << 16); }
__device__ __forceinline__ float bf_hi(unsigned v) { return __uint_as_float(v & 0xffff0000u); }

// ---------------------------------------------------------------- zero init
__global__ __launch_bounds__(256) void zero_init(uint4* h16) {
  int i = blockIdx.x * 256 + threadIdx.x;
  uint4 z; z.x = z.y = z.z = z.w = 0u;
  if (i < 32768) h16[i] = z;            // hb0: 262144 bf16 = 32768 x 16B
}
__global__ __launch_bounds__(256) void zero_flags(unsigned* flags) {
  flags[blockIdx.x * 256 + threadIdx.x] = 0u;   // 1024 dwords (flags+counters)
}

// ------------------------------------------------- transpose+cast [1024][4096]
__global__ __launch_bounds__(256) void transpose_cast(const float* __restrict__ in,
                                                      __bf16* __restrict__ out) {
  __shared__ __bf16 tile[32][33];
  const int c0 = blockIdx.x * 32;
  const int r0 = blockIdx.y * 32;
  const int tx = threadIdx.x & 31, ty = threadIdx.x >> 5;
#pragma unroll
  for (int p = 0; p < 4; ++p) {
    const int rr = ty + p * 8;
    tile[rr][tx] = (__bf16)in[(size_t)(r0 + rr) * G_ + c0 + tx];
  }
  __syncthreads();
#pragma unroll
  for (int p = 0; p < 4; ++p) {
    const int rr = ty + p * 8;
    out[(size_t)(c0 + rr) * E_ + r0 + tx] = tile[tx][rr];
  }
}

// ------------------------------------------------------- embedding gather+cast
union U16b { uint4 v; __bf16 h[8]; };
__global__ __launch_bounds__(256) void gather_cast(const int* __restrict__ idx,
                                                   const float* __restrict__ emb,
                                                   __bf16* __restrict__ X) {
  const size_t gid  = (size_t)blockIdx.x * 256 + threadIdx.x;
  const size_t base = gid * 8;
  const int r = (int)(base >> 10);
  const int e = (int)(base & 1023);
  const int row = idx[r];
  const float4* s = (const float4*)(emb + (size_t)row * E_ + e);
  const float4 v0 = s[0], v1 = s[1];
  U16b u;
  u.h[0] = (__bf16)v0.x; u.h[1] = (__bf16)v0.y; u.h[2] = (__bf16)v0.z; u.h[3] = (__bf16)v0.w;
  u.h[4] = (__bf16)v1.x; u.h[5] = (__bf16)v1.y; u.h[6] = (__bf16)v1.z; u.h[7] = (__bf16)v1.w;
  *(uint4*)(X + base) = u.v;
}

// --------------------------------------------------- xW GEMM (m97 structure)
// Writes XW PERMUTED: elem offset = ((row*32 + cg)*4 + gate)*32 + col_in_cg.
__global__ __launch_bounds__(256) void gemm_xw(const __bf16* __restrict__ X,
                                               const __bf16* __restrict__ WiT,
                                               const float* __restrict__ bias,
                                               __bf16* __restrict__ XW2) {
  __shared__ __bf16 As[128 * 32];
  __shared__ __bf16 Bs[128 * 32];
  __shared__ __bf16 eps[64][136];
  const int tid = threadIdx.x;
  const int lane = tid & 63;
  const int wid = tid >> 6;
  const int bn = blockIdx.x & 31;
  const int bm = blockIdx.x >> 5;
  const int row0 = bm * 128, col0 = bn * 128;
  const int wr = (wid >> 1) * 64, wc = (wid & 1) * 64;
  const int srow = tid >> 2, schunk = tid & 3;
  const char* gA = (const char*)(X + (size_t)(row0 + srow) * E_) + schunk * 16;
  const char* gB = (const char*)(WiT + (size_t)(col0 + srow) * E_) + schunk * 16;
  char* lA = (char*)As + wid * 1024;
  char* lB = (char*)Bs + wid * 1024;
  const int fr = lane & 15, kb = lane >> 4;

  f32x4 acc[4][4] = {};

  for (int kt = 0; kt < 32; ++kt) {
    gload_lds16(gA + kt * 64,              lA);
    gload_lds16(gA + kt * 64 + 64 * 2048,  lA + 4096);
    gload_lds16(gB + kt * 64,              lB);
    gload_lds16(gB + kt * 64 + 64 * 2048,  lB + 4096);
    __syncthreads();
    bf16x8 a[4], b[4];
#pragma unroll
    for (int m = 0; m < 4; ++m)
      a[m] = *(const bf16x8*)((const char*)As + (wr + m * 16 + fr) * 64 + kb * 16);
#pragma unroll
    for (int n = 0; n < 4; ++n)
      b[n] = *(const bf16x8*)((const char*)Bs + (wc + n * 16 + fr) * 64 + kb * 16);
#pragma unroll
    for (int m = 0; m < 4; ++m)
#pragma unroll
      for (int n = 0; n < 4; ++n)
        acc[m][n] = MFMA16(a[m], b[n], acc[m][n]);
    __syncthreads();
  }

  float bv[4];
#pragma unroll
  for (int n = 0; n < 4; ++n) bv[n] = bias[col0 + wc + n * 16 + fr];

  const int gate = col0 >> 10;             // 128-col tile spans one gate
  const int cg0  = (col0 & 1023) >> 5;     // first of 4 col-groups

#pragma unroll
  for (int h = 0; h < 2; ++h) {
    if ((wid >> 1) == h) {
#pragma unroll
      for (int m = 0; m < 4; ++m)
#pragma unroll
        for (int n = 0; n < 4; ++n)
#pragma unroll
          for (int r = 0; r < 4; ++r)
            eps[m * 16 + kb * 4 + r][wc + n * 16 + fr] = (__bf16)(acc[m][n][r] + bv[n]);
    }
    __syncthreads();
    {
      const int row = tid >> 2, ch = tid & 3;
      const int r_m = row0 + h * 64 + row;
      const uint4* s = (const uint4*)&eps[row][ch * 32];
      uint4* d = (uint4*)(XW2 + ((size_t)r_m * 32 + (cg0 + ch)) * 128 + gate * 32);
#pragma unroll
      for (int i = 0; i < 4; ++i) d[i] = s[i];
    }
    __syncthreads();
  }
}

// ----------------------------------------------------- persistent LSTM scan
// 256 blocks (1/CU), 512 threads. Block = 32 batch rows x 32 h-cols.
// Wave = (gate wg, K-half kh): 32 cols x 512 K each, W[2][16] in registers.
// bg group == XCD; h through own L2 (sc0); flags via agent atomics (proven).
__global__ __launch_bounds__(512, 2) void lstm_scan(
    const __bf16* __restrict__ WhT, const __bf16* __restrict__ XW2,
    __bf16* __restrict__ hb0, __bf16* __restrict__ hb1,
    float* __restrict__ outp, float* __restrict__ hfin,
    float* __restrict__ cfin, unsigned* __restrict__ flags) {
  __shared__ __bf16 As[32 * 1024];     // 64 KB, XOR-swizzled 16B chunks
  __shared__ float  zs2[2][4][32][34]; // per-K-half gate partials (34KB)
  __shared__ int    sgrp[2];
  const int tid = threadIdx.x;
  const int lane = tid & 63;
  const int wid = tid >> 6;

  // ---- runtime XCD grouping: bg = XCC_ID, cg = slot within the XCD ----
  if (tid == 0) {
    unsigned xcd;
    asm volatile("s_getreg_b32 %0, hwreg(HW_REG_XCC_ID)" : "=s"(xcd));
    xcd &= 7u;
    unsigned slot = __hip_atomic_fetch_add(&flags[512 + xcd], 1u,
                                           __ATOMIC_RELAXED, __HIP_MEMORY_SCOPE_AGENT);
    sgrp[0] = (int)xcd;
    sgrp[1] = (int)(slot & 31u);
  }
  __syncthreads();
  const int bg = sgrp[0];
  const int cg = sgrp[1];
  const int b0 = bg * 32;
  const int c0 = cg * 32;
  unsigned* grpflags = flags + bg * 64;        // 32 flags, 2 cachelines/group

  const int wg = wid & 3;      // gate (i,f,g,o)
  const int kh = wid >> 2;     // K half: [kh*512, kh*512+512)
  const int fr = lane & 15, kb = lane >> 4;

  // ---- Wh slice -> registers, once: cols c0..c0+32, K-half kh ----
  bf16x8 W[2][16];
  {
    const __bf16* wbase = WhT + (size_t)(wg * 1024 + c0) * H_ + kh * 512 + kb * 8;
#pragma unroll
    for (int n = 0; n < 2; ++n)
#pragma unroll
      for (int j = 0; j < 16; ++j)
        W[n][j] = *(const bf16x8*)(wbase + (size_t)(n * 16 + fr) * H_ + j * 32);
  }

  const int crow = tid >> 4, ccolb = (tid & 15) * 2;
  const size_t sidx = (size_t)(b0 + crow) * H_ + c0 + ccolb;
  const __bf16* xwrow = XW2 + ((size_t)(b0 + crow) * S_ * 32 + cg) * 128 + ccolb;
  float creg0 = 0.f, creg1 = 0.f;

#pragma unroll 1
  for (int t = 0; t < S_; ++t) {
    const __bf16* hin = (t & 1) ? hb1 : hb0;
    __bf16* hout = (t & 1) ? hb0 : hb1;

    // XW cell inputs for step t (plain cached loads, issued early).
    const __bf16* p = xwrow + (size_t)t * 4096;
    const unsigned xw0 = *(const unsigned*)(p);
    const unsigned xw1 = *(const unsigned*)(p + 32);
    const unsigned xw2 = *(const unsigned*)(p + 64);
    const unsigned xw3 = *(const unsigned*)(p + 96);

    // ---- wait for h(t-1) of OUR bg group (proven atomic poll) ----
    if (t > 0) {
      if (tid < 32) {
        const unsigned tgt = (unsigned)t;
        while (__hip_atomic_load(&grpflags[tid], __ATOMIC_RELAXED,
                                 __HIP_MEMORY_SCOPE_AGENT) < tgt)
          __builtin_amdgcn_s_sleep(1);
      }
      __syncthreads();
    }

    // ---- stage h rows [b0,b0+32): sc0 loads -> swizzled ds_write ----
    {
      uint4 sv[8];
#pragma unroll
      for (int i = 0; i < 8; ++i) {
        const int ci = i * 512 + tid;
        const int row = ci >> 7, cch = ci & 127;
        const void* src = (const char*)(hin + (size_t)(b0 + row) * H_) + cch * 16;
        asm volatile("global_load_dwordx4 %0, %1, off sc0"
                     : "=&v"(sv[i]) : "v"(src) : "memory");
      }
      asm volatile("s_waitcnt vmcnt(0)" ::: "memory");
      __builtin_amdgcn_sched_barrier(0);
#pragma unroll
      for (int i = 0; i < 8; ++i) {
        const int ci = i * 512 + tid;
        const int row = ci >> 7, cch = ci & 127;
        *(uint4*)((char*)As + row * 2048 + ((cch ^ (row & 7)) * 16)) = sv[i];
      }
    }
    __syncthreads();

    // ---- MFMA: 32 rows x 32 cols x 512 K per wave; 1 A-read -> 4 MFMA ----
    f32x4 acc[2][2] = {};   // [row-half][col-half]
#pragma unroll
    for (int j = 0; j < 16; ++j) {
      const int ck = kh * 64 + j * 4 + kb;
      bf16x8 alo = *(const bf16x8*)((const char*)As + fr * 2048 +
                                    ((ck ^ (fr & 7)) * 16));
      bf16x8 ahi = *(const bf16x8*)((const char*)As + (16 + fr) * 2048 +
                                    ((ck ^ (fr & 7)) * 16));
      acc[0][0] = MFMA16(alo, W[0][j], acc[0][0]);
      acc[0][1] = MFMA16(alo, W[1][j], acc[0][1]);
      acc[1][0] = MFMA16(ahi, W[0][j], acc[1][0]);
      acc[1][1] = MFMA16(ahi, W[1][j], acc[1][1]);
    }

    // ---- merged reduce: each kh writes its own layer, cell adds both ----
#pragma unroll
    for (int rh = 0; rh < 2; ++rh)
#pragma unroll
      for (int n = 0; n < 2; ++n)
#pragma unroll
        for (int r = 0; r < 4; ++r)
          zs2[kh][wg][rh * 16 + kb * 4 + r][n * 16 + fr] = acc[rh][n][r];
    __syncthreads();

    // ---- cell (fp32), c in registers ----
    const float2 zi2a = *(const float2*)&zs2[0][0][crow][ccolb];
    const float2 zf2a = *(const float2*)&zs2[0][1][crow][ccolb];
    const float2 zg2a = *(const float2*)&zs2[0][2][crow][ccolb];
    const float2 zo2a = *(const float2*)&zs2[0][3][crow][ccolb];
    const float2 zi2b = *(const float2*)&zs2[1][0][crow][ccolb];
    const float2 zf2b = *(const float2*)&zs2[1][1][crow][ccolb];
    const float2 zg2b = *(const float2*)&zs2[1][2][crow][ccolb];
    const float2 zo2b = *(const float2*)&zs2[1][3][crow][ccolb];
    const float zi0 = zi2a.x + zi2b.x + bf_lo(xw0), zi1 = zi2a.y + zi2b.y + bf_hi(xw0);
    const float zf0 = zf2a.x + zf2b.x + bf_lo(xw1), zf1 = zf2a.y + zf2b.y + bf_hi(xw1);
    const float zg0 = zg2a.x + zg2b.x + bf_lo(xw2), zg1 = zg2a.y + zg2b.y + bf_hi(xw2);
    const float zo0 = zo2a.x + zo2b.x + bf_lo(xw3), zo1 = zo2a.y + zo2b.y + bf_hi(xw3);
    const float cv0 = sigm(zf0) * creg0 + sigm(zi0) * tanhfast(zg0);
    const float cv1 = sigm(zf1) * creg1 + sigm(zi1) * tanhfast(zg1);
    creg0 = cv0; creg1 = cv1;
    const float hv0 = sigm(zo0) * tanhfast(cv0);
    const float hv1 = sigm(zo1) * tanhfast(cv1);

    union { __bf16 h[2]; unsigned u; } up;
    up.h[0] = (__bf16)hv0; up.h[1] = (__bf16)hv1;
    float2 o2; o2.x = hv0; o2.y = hv1;

    // h store: sc0-only -> lands in our XCD's L2 (consumers are same-XCD)
    {
      void* dst = (void*)(hout + sidx);
      asm volatile("global_store_dword %0, %1, off sc0"
                   :: "v"(dst), "v"(up.u) : "memory");
    }

    if (t == S_ - 1) {
      *(float2*)(outp + ((size_t)(b0 + crow) * S_ + t) * H_ + c0 + ccolb) = o2;
      float2 c2; c2.x = cv0; c2.y = cv1;
      *(float2*)(hfin + sidx) = o2;
      *(float2*)(cfin + sidx) = c2;
    } else {
      asm volatile("s_waitcnt vmcnt(0)" ::: "memory");   // h committed to L2
      __builtin_amdgcn_s_barrier();
      if (tid == 0)
        __hip_atomic_store(&grpflags[cg], (unsigned)(t + 1),
                           __ATOMIC_RELAXED, __HIP_MEMORY_SCOPE_AGENT);
      // outp store AFTER the flag: a full step of slack to drain
      *(float2*)(outp + ((size_t)(b0 + crow) * S_ + t) * H_ + c0 + ccolb) = o2;
    }
  }
}

// ----------------------------------------------------------------- launcher
extern "C" void kernel_launch(void* const* d_in, const int* in_sizes, int n_in,
                              void* d_out, int out_size, void* d_ws, size_t ws_size,
                              hipStream_t stream) {
  const int*   inp  = (const int*)d_in[0];
  const float* emb  = (const float*)d_in[1];
  const float* Wi   = (const float*)d_in[2];
  const float* Wh   = (const float*)d_in[3];
  const float* bias = (const float*)d_in[4];

  char* ws = (char*)d_ws;
  __bf16* WiT = (__bf16*)(ws);
  __bf16* WhT = (__bf16*)(ws + 8388608);
  __bf16* hb0 = (__bf16*)(ws + 16777216);
  __bf16* hb1 = (__bf16*)(ws + 17301504);
  __bf16* X   = (__bf16*)(ws + 17825792);
  __bf16* XW2 = (__bf16*)(ws + 152043520);
  unsigned* flags = (unsigned*)(ws + 17825792);  // overlays dead X during scan

  float* outp = (float*)d_out;
  float* hfin = outp + (size_t)M_ * H_;
  float* cfin = hfin + (size_t)B_ * H_;

  zero_init<<<128, 256, 0, stream>>>((uint4*)hb0);
  transpose_cast<<<dim3(128, 32), 256, 0, stream>>>(Wi, WiT);
  transpose_cast<<<dim3(128, 32), 256, 0, stream>>>(Wh, WhT);
  gather_cast<<<32768, 256, 0, stream>>>(inp, emb, X);
  gemm_xw<<<16384, 256, 0, stream>>>(X, WiT, bias, XW2);
  zero_flags<<<4, 256, 0, stream>>>(flags);   // X is dead from here on
  lstm_scan<<<256, 512, 0, stream>>>(WhT, XW2, hb0, hb1, outp, hfin, cfin, flags);
}